// Round 7
// baseline (261.692 us; speedup 1.0000x reference)
//
#include <hip/hip_runtime.h>
#include <hip/hip_bf16.h>

#define NN 8
#define TT 192
#define HH 1024
#define DD 128
#define TPP 48
#define EE 16384
#define NEDGE (EE + HH)      // 17408
#define BB (NN * TPP)        // 384
#define NOUT (NN * TT * DD)  // 196608
#define NBLK 512

typedef short bf16x8 __attribute__((ext_vector_type(8)));
typedef float f32x4 __attribute__((ext_vector_type(4)));

struct KParams {
  const float* x; const int* xm; const int* edges; const int* node_split;
  const float* hour_emb; const float* wday_emb; const float* tw; const float* tw_b;
  const float* tcw; const float* tcb; const float* W1; const float* b1;
  const float* W2; const float* b2;
  float* out;
  int* degE; int* bar; float* zbuf; float* csum; float* QT;
  int* row_ptr; int* inv; int* csr_src; float* csr_coef; int* fill;
  __hip_bfloat16* w2sw; float* CW; float* twT;
  __hip_bfloat16* Xall; __hip_bfloat16* xbar; float* ypar;
};

__device__ __forceinline__ float us2f(unsigned short u) {
  union { unsigned i; float f; } t;
  t.i = ((unsigned)u) << 16;
  return t.f;
}

// hierarchical device-scope grid barrier: 64 sub-counters (64B apart) -> master -> gen
__device__ __forceinline__ void gridbar(int* bar) {
  __syncthreads();
  if (threadIdx.x == 0) {
    __threadfence();  // release: flush this XCD's dirty L2 to device scope
    int gen = __hip_atomic_load(&bar[0], __ATOMIC_RELAXED, __HIP_MEMORY_SCOPE_AGENT);
    int sub = blockIdx.x & 63;
    int t = atomicAdd(&bar[32 + sub * 16], 1);
    if (t == (NBLK / 64) - 1) {
      atomicExch(&bar[32 + sub * 16], 0);
      int m = atomicAdd(&bar[16], 1);
      if (m == 63) {
        atomicExch(&bar[16], 0);
        atomicAdd(&bar[0], 1);
      } else {
        while (__hip_atomic_load(&bar[0], __ATOMIC_RELAXED, __HIP_MEMORY_SCOPE_AGENT) == gen)
          __builtin_amdgcn_s_sleep(1);
      }
    } else {
      while (__hip_atomic_load(&bar[0], __ATOMIC_RELAXED, __HIP_MEMORY_SCOPE_AGENT) == gen)
        __builtin_amdgcn_s_sleep(1);
    }
    __threadfence();  // acquire: invalidate stale clean lines before next phase reads
  }
  __syncthreads();
}

__global__ __launch_bounds__(256, 2) void k_mega(KParams P) {
  __shared__ __align__(16) char U[49152];
  int tid = threadIdx.x;
  int bid = blockIdx.x;

  // ================= P0: deg atomics, inv, twT, zeros, x transpose =================
  if (bid < 256) {
    int i = bid * 256 + tid;
    if (i < EE) atomicAdd(&P.degE[P.edges[2 * i + 1]], 1);
    if (i < HH) P.inv[P.node_split[i]] = i;
    P.twT[(i & 511) * DD + (i >> 9)] = P.tw[i];  // i < 65536 exactly
    if (i < 6144) P.zbuf[i] = 0.f;               // fill|csum|QT
  }
  if (bid < 384) {
    float(*tile)[65] = (float(*)[65])U;
    int tt = bid % 24, st = bid / 24;
    int t0 = tt * 64, s0 = st * 64;
    int sl = tid & 63, r4 = tid >> 6;
#pragma unroll 4
    for (int ii = 0; ii < 16; ++ii) {
      int tl = ii * 4 + r4;
      tile[tl][sl] = P.x[(size_t)(t0 + tl) * HH + s0 + sl];
    }
    __syncthreads();
#pragma unroll 4
    for (int ii = 0; ii < 16; ++ii) {
      int sl2 = ii * 4 + r4;
      P.Xall[(size_t)(s0 + sl2) * 1536 + t0 + sl] = __float2bfloat16(tile[sl][sl2]);
    }
  }
  gridbar(P.bar);

  // ================= P1: scan | time-emb | CW | W2 swizzle =================
  if (bid == 0) {
    int t4 = tid * 4;
    int v0 = P.degE[t4] + 1, v1 = P.degE[t4 + 1] + 1;
    int v2 = P.degE[t4 + 2] + 1, v3 = P.degE[t4 + 3] + 1;
    int s_ = v0 + v1 + v2 + v3;
    int lane = tid & 63, wid = tid >> 6;
    int inc = s_;
#pragma unroll
    for (int off = 1; off < 64; off <<= 1) {
      int u = __shfl_up(inc, off, 64);
      if (lane >= off) inc += u;
    }
    int* wsum = (int*)U;
    if (lane == 63) wsum[wid] = inc;
    __syncthreads();
    int wb = 0;
    for (int ww = 0; ww < wid; ++ww) wb += wsum[ww];
    int ex = wb + inc - s_;
    P.row_ptr[t4 + 1] = ex + v0;
    P.row_ptr[t4 + 2] = ex + v0 + v1;
    P.row_ptr[t4 + 3] = ex + v0 + v1 + v2;
    P.row_ptr[t4 + 4] = ex + s_;
    if (tid == 0) P.row_ptr[0] = 0;
  } else if (bid <= 192) {
    int u = bid - 1;  // time unit: 2 b's
    float(*sL)[512] = (float(*)[512])U;
    int half = tid >> 7, o = tid & 127;
    int b = u * 2 + half;
    int n = b / TPP, tp = b % TPP;
    for (int k = 0; k < 4; ++k) {
      int t = tp * 4 + k;
      int wd = P.xm[(n * TT + t) * 2 + 0];
      int hr = P.xm[(n * TT + t) * 2 + 1];
      sL[half][o * 4 + k] = P.hour_emb[hr * DD + o] + P.wday_emb[wd * DD + o];
    }
    __syncthreads();
    float a0 = P.tw_b[o], a1 = 0.f, a2 = 0.f, a3 = 0.f;
    for (int j = 0; j < 512; j += 4) {
      a0 = fmaf(sL[half][j + 0], P.twT[(j + 0) * DD + o], a0);
      a1 = fmaf(sL[half][j + 1], P.twT[(j + 1) * DD + o], a1);
      a2 = fmaf(sL[half][j + 2], P.twT[(j + 2) * DD + o], a2);
      a3 = fmaf(sL[half][j + 3], P.twT[(j + 3) * DD + o], a3);
    }
    float acc = (a0 + a1) + (a2 + a3);
    size_t base = (size_t)NOUT + ((size_t)n * TT + tp * 4) * DD + o;
    P.out[base] = acc;
    P.out[base + DD] = acc;
    P.out[base + 2 * DD] = acc;
    P.out[base + 3 * DD] = acc;
  } else if (bid <= 195) {
    int j = (bid - 193) * 256 + tid;
    if (j < 640) {
      int jr = j >> 7, o = j & 127;
      float acc = 0.f;
      if (jr < 4)
        for (int d = 0; d < DD; ++d) acc = fmaf(P.tcw[d * 4 + jr], P.W1[d * DD + o], acc);
      else
        for (int d = 0; d < DD; ++d) acc = fmaf(P.tcb[d], P.W1[d * DD + o], acc);
      P.CW[jr * DD + o] = acc;
    }
  } else if (bid < 260) {
    int i = (bid - 196) * 256 + tid;  // < 16384
    int n = i >> 7, k = i & 127;
    int dstb = n * 256 + (((k >> 3) ^ (n & 7)) * 16) + (k & 7) * 2;
    P.w2sw[dstb >> 1] = __float2bfloat16(P.W2[k * DD + n]);
  }
  gridbar(P.bar);

  // ================= P2: scatter =================
  if (bid < 68) {
    int e = bid * 256 + tid;
    if (e < NEDGE) {
      int s, dt;
      if (e < EE) { s = P.edges[2 * e]; dt = P.edges[2 * e + 1]; }
      else        { s = dt = e - EE; }
      float ds = (float)(P.degE[s] + 1);
      float dd = (float)(P.degE[dt] + 1);
      float cf = rsqrtf(ds * dd);
      int pos = atomicAdd(&P.fill[dt], 1);
      int at = P.row_ptr[dt] + pos;
      P.csr_src[at] = s;
      P.csr_coef[at] = cf;
      atomicAdd(&P.csum[dt], cf);
      int g = P.inv[dt] >> 8;
      atomicAdd(&P.QT[s * 4 + g], cf * (1.0f / 256.0f));
    }
  }
  gridbar(P.bar);

  // ================= P3: SpMM, one row per half-block =================
  {
    int h = bid * 2 + (tid >> 7);
    int c = tid & 127;
    int j0 = P.row_ptr[h], j1 = P.row_ptr[h + 1];
    float a[12];
#pragma unroll
    for (int u = 0; u < 12; ++u) a[u] = 0.f;
    for (int j = j0; j < j1; ++j) {
      int s = P.csr_src[j];
      float cf = P.csr_coef[j];
      const unsigned* xr = (const unsigned*)(P.Xall + (size_t)s * 1536);
#pragma unroll
      for (int u = 0; u < 6; ++u) {
        unsigned v = xr[c + u * 128];
        union { unsigned i; float f; } lo, hi;
        lo.i = v << 16;
        hi.i = v & 0xffff0000u;
        a[2 * u] = fmaf(cf, lo.f, a[2 * u]);
        a[2 * u + 1] = fmaf(cf, hi.f, a[2 * u + 1]);
      }
    }
    unsigned* xw = (unsigned*)(P.xbar + (size_t)h * 1536);
#pragma unroll
    for (int u = 0; u < 6; ++u) {
      union { __hip_bfloat16 h2[2]; unsigned u2; } pk;
      pk.h2[0] = __float2bfloat16(a[2 * u]);
      pk.h2[1] = __float2bfloat16(a[2 * u + 1]);
      xw[c + u * 128] = pk.u2;
    }
  }
  gridbar(P.bar);

  // ================= P4: red, 3 units per block =================
  for (int uu = 0; uu < 3; ++uu) {
    int unit = bid + uu * NBLK;  // < 1536
    int b = unit >> 2, qt = unit & 3;
    int h = qt * 256 + tid;
    float4* xb4 = (float4*)U;
    float4* qv = (float4*)(U + 4096);
    float* csv = (float*)(U + 8192);
    float* yL = (float*)(U + 9216);
    {
      ushort4 us = *(const ushort4*)(P.xbar + (size_t)h * 1536 + b * 4);
      xb4[tid] = make_float4(us2f(us.x), us2f(us.y), us2f(us.z), us2f(us.w));
      qv[tid] = *(const float4*)(P.QT + h * 4);
      csv[tid] = P.csum[h];
    }
    int o = tid & 127, sub = tid >> 7;
    float cw0 = P.CW[o], cw1 = P.CW[DD + o], cw2 = P.CW[2 * DD + o];
    float cw3 = P.CW[3 * DD + o], cw4 = P.CW[4 * DD + o];
    float b1o = P.b1[o];
    __syncthreads();
    float y0 = 0.f, y1 = 0.f, y2 = 0.f, y3 = 0.f;
    int hh0 = sub * 128;
#pragma unroll 4
    for (int hh = hh0; hh < hh0 + 128; ++hh) {
      float4 xv = xb4[hh];
      float4 q = qv[hh];
      float cc = csv[hh];
      float t = fmaf(cc, cw4, b1o);
      t = fmaf(xv.x, cw0, t);
      t = fmaf(xv.y, cw1, t);
      t = fmaf(xv.z, cw2, t);
      t = fmaf(xv.w, cw3, t);
      t = fmaxf(t, 0.f);
      y0 = fmaf(q.x, t, y0);
      y1 = fmaf(q.y, t, y1);
      y2 = fmaf(q.z, t, y2);
      y3 = fmaf(q.w, t, y3);
    }
    if (sub == 0) {
      yL[o] = y0; yL[DD + o] = y1; yL[2 * DD + o] = y2; yL[3 * DD + o] = y3;
    }
    __syncthreads();
    if (sub == 1) {
      yL[o] += y0; yL[DD + o] += y1; yL[2 * DD + o] += y2; yL[3 * DD + o] += y3;
    }
    __syncthreads();
    float* yp = P.ypar + ((size_t)qt * BB + b) * 512;
    yp[tid] = yL[tid];
    yp[tid + 256] = yL[tid + 256];
    __syncthreads();  // yL reads done before next unit overwrites U
  }
  gridbar(P.bar);

  // ================= P5: out GEMM (blocks 0..23) =================
  if (bid < 24) {
    char* Wr = U;
    char* Gr = U + 32768;
    int m0 = bid * 64;
    {
      const uint4* ws = (const uint4*)P.w2sw;
      uint4* wd = (uint4*)Wr;
      for (int i = tid; i < 2048; i += 256) wd[i] = ws[i];
    }
#pragma unroll 4
    for (int it = 0; it < 16; ++it) {
      int pi = it * 256 + tid;
      int row = pi >> 6, kp = pi & 63;
      int base = (m0 + row) * 128 + 2 * kp;
      float s0 = 0.f, s1 = 0.f;
#pragma unroll
      for (int p = 0; p < 4; ++p) {
        s0 += P.ypar[(size_t)p * (BB * 512) + base];
        s1 += P.ypar[(size_t)p * (BB * 512) + base + 1];
      }
      union { __hip_bfloat16 h[2]; unsigned u; } pk;
      pk.h[0] = __float2bfloat16(s0);
      pk.h[1] = __float2bfloat16(s1);
      *(unsigned*)(Gr + row * 256 + (((kp >> 2) ^ (row & 7)) * 16) + (kp & 3) * 4) = pk.u;
    }
    int lane = tid & 63, w = tid >> 6;
    int colq = lane & 15, quad = lane >> 4;
    float bo[8];
#pragma unroll
    for (int jn = 0; jn < 8; ++jn) bo[jn] = P.b2[jn * 16 + colq];
    __syncthreads();

    f32x4 acc[8];
#pragma unroll
    for (int jn = 0; jn < 8; ++jn) acc[jn] = (f32x4){0.f, 0.f, 0.f, 0.f};
    int arow = w * 16 + colq;
#pragma unroll
    for (int kc = 0; kc < 4; ++kc) {
      bf16x8 af = *(const bf16x8*)(Gr + arow * 256 + (((kc * 4 + quad) ^ (arow & 7)) * 16));
#pragma unroll
      for (int jn = 0; jn < 8; ++jn) {
        int nr = jn * 16 + colq;
        bf16x8 bf = *(const bf16x8*)(Wr + nr * 256 + (((kc * 4 + quad) ^ (nr & 7)) * 16));
        acc[jn] = __builtin_amdgcn_mfma_f32_16x16x32_bf16(af, bf, acc[jn], 0, 0, 0);
      }
    }
#pragma unroll
    for (int reg = 0; reg < 4; ++reg) {
      int m = m0 + w * 16 + quad * 4 + reg;
      int b = m >> 2, g = m & 3;
      int n_ = b / TPP, tp = b % TPP;
      size_t rb = ((size_t)(n_ * TT + tp * 4 + g)) * DD;
#pragma unroll
      for (int jn = 0; jn < 8; ++jn) {
        int o = jn * 16 + colq;
        P.out[rb + o] = acc[jn][reg] + bo[jn] + P.out[(size_t)NOUT + rb + o];
      }
    }
  }
}

extern "C" void kernel_launch(void* const* d_in, const int* in_sizes, int n_in,
                              void* d_out, int out_size, void* d_ws, size_t ws_size,
                              hipStream_t stream) {
  char* w = (char*)d_ws;
  KParams P;
  P.x = (const float*)d_in[0];
  P.xm = (const int*)d_in[1];
  P.edges = (const int*)d_in[2];
  P.node_split = (const int*)d_in[3];
  P.hour_emb = (const float*)d_in[4];
  P.wday_emb = (const float*)d_in[5];
  P.tw = (const float*)d_in[6];
  P.tw_b = (const float*)d_in[7];
  P.tcw = (const float*)d_in[8];
  P.tcb = (const float*)d_in[9];
  P.W1 = (const float*)d_in[10];
  P.b1 = (const float*)d_in[11];
  P.W2 = (const float*)d_in[12];
  P.b2 = (const float*)d_in[13];
  P.out = (float*)d_out;

  P.degE = (int*)(w + 0);                    //    4096 B (memset)
  P.bar = (int*)(w + 4096);                  //    8192 B (memset)
  P.zbuf = (float*)(w + 12288);              //   24576 B = fill|csum|QT (zeroed P0)
  P.fill = (int*)(w + 12288);                //    4096 B
  P.csum = (float*)(w + 16384);              //    4096 B
  P.QT = (float*)(w + 20480);                //   16384 B
  P.row_ptr = (int*)(w + 36864);             //    4352 B
  P.inv = (int*)(w + 41216);                 //    4096 B
  P.csr_src = (int*)(w + 45312);             //   69632 B
  P.csr_coef = (float*)(w + 114944);         //   69632 B
  P.w2sw = (__hip_bfloat16*)(w + 184576);    //   32768 B
  P.CW = (float*)(w + 217344);               //    4096 B
  P.twT = (float*)(w + 221440);              //  262144 B
  P.Xall = (__hip_bfloat16*)(w + 483584);    // 3145728 B
  P.xbar = (__hip_bfloat16*)(w + 3629312);   // 3145728 B
  P.ypar = (float*)(w + 6775040);            // 3145728 B (end ~9.92 MB)

  hipMemsetAsync(d_ws, 0, 12288, stream);  // degE + barrier state
  k_mega<<<NBLK, 256, 0, stream>>>(P);
}

// Round 8
// 207.455 us; speedup vs baseline: 1.2614x; 1.2614x over previous
//
#include <hip/hip_runtime.h>
#include <hip/hip_bf16.h>

#define NN 8
#define TT 192
#define HH 1024
#define DD 128
#define TPP 48
#define EE 16384
#define NEDGE (EE + HH)      // 17408
#define BB (NN * TPP)        // 384
#define NOUT (NN * TT * DD)  // 196608

// ================= K0: prep =================
// bid 0: CSR build entirely in LDS (deg -> scan -> scatter -> csum/QT), one block.
// bid 1: CW = Conv@W1 (5 x 128).
// bid 2..129: twT transpose (tw[o][ck] -> twT[ck][o]).
__global__ __launch_bounds__(256) void k_prep(
    const int* __restrict__ edges, const int* __restrict__ node_split,
    const float* __restrict__ tcw, const float* __restrict__ tcb,
    const float* __restrict__ W1, const float* __restrict__ tw,
    int* __restrict__ row_ptr, int* __restrict__ csr_src,
    float* __restrict__ csr_coef, float* __restrict__ csum,
    float* __restrict__ QT, float* __restrict__ CW, float* __restrict__ twT) {
  int tid = threadIdx.x, bid = blockIdx.x;
  if (bid == 0) {
    __shared__ int degL[1024];
    __shared__ int fillL[1024];
    __shared__ float csumL[1024];
    __shared__ float QTL[4096];
    __shared__ int rpL[1028];
    __shared__ int invL[1024];
    __shared__ int wsumL[4];
    for (int i = tid; i < 4096; i += 256) {
      QTL[i] = 0.f;
      if (i < 1024) { degL[i] = 0; fillL[i] = 0; csumL[i] = 0.f; }
    }
    for (int i = tid; i < 1024; i += 256) invL[node_split[i]] = i;
    __syncthreads();
    for (int e = tid; e < EE; e += 256) atomicAdd(&degL[edges[2 * e + 1]], 1);
    __syncthreads();
    // exclusive scan of (deg+1) -> rpL
    int t4 = tid * 4;
    int v0 = degL[t4] + 1, v1 = degL[t4 + 1] + 1;
    int v2 = degL[t4 + 2] + 1, v3 = degL[t4 + 3] + 1;
    int s_ = v0 + v1 + v2 + v3;
    int lane = tid & 63, wid = tid >> 6;
    int inc = s_;
#pragma unroll
    for (int off = 1; off < 64; off <<= 1) {
      int u = __shfl_up(inc, off, 64);
      if (lane >= off) inc += u;
    }
    if (lane == 63) wsumL[wid] = inc;
    __syncthreads();
    int wb = 0;
    for (int ww = 0; ww < wid; ++ww) wb += wsumL[ww];
    int ex = wb + inc - s_;
    rpL[t4 + 1] = ex + v0;
    rpL[t4 + 2] = ex + v0 + v1;
    rpL[t4 + 3] = ex + v0 + v1 + v2;
    rpL[t4 + 4] = ex + s_;
    if (tid == 0) rpL[0] = 0;
    __syncthreads();
    for (int i = tid; i < 1025; i += 256) row_ptr[i] = rpL[i];
    // scatter
    for (int e = tid; e < NEDGE; e += 256) {
      int s, dt;
      if (e < EE) { s = edges[2 * e]; dt = edges[2 * e + 1]; }
      else        { s = dt = e - EE; }
      float cf = rsqrtf((float)(degL[s] + 1) * (float)(degL[dt] + 1));
      int pos = atomicAdd(&fillL[dt], 1);
      int at = rpL[dt] + pos;
      csr_src[at] = s;
      csr_coef[at] = cf;
      atomicAdd(&csumL[dt], cf);
      atomicAdd(&QTL[s * 4 + (invL[dt] >> 8)], cf * (1.0f / 256.0f));
    }
    __syncthreads();
    for (int i = tid; i < 4096; i += 256) {
      QT[i] = QTL[i];
      if (i < 1024) csum[i] = csumL[i];
    }
  } else if (bid == 1) {
    // CW[j][o] = sum_d Conv[j][d]*W1[d][o];  Conv[j<4][d]=tcw[d*4+j], Conv[4][d]=tcb[d]
    for (int j = tid; j < 640; j += 256) {
      int jr = j >> 7, o = j & 127;
      float acc = 0.f;
      if (jr < 4)
        for (int d = 0; d < DD; ++d) acc = fmaf(tcw[d * 4 + jr], W1[d * DD + o], acc);
      else
        for (int d = 0; d < DD; ++d) acc = fmaf(tcb[d], W1[d * DD + o], acc);
      CW[jr * DD + o] = acc;
    }
  } else {
    int base = (bid - 2) * 512;
    for (int ii = base + tid; ii < base + 512; ii += 256)
      twT[(ii & 511) * DD + (ii >> 9)] = tw[ii];
  }
}

// ================= K1: fused gather + conv-fold + Q-reduce + time + W2 =================
// One block per b. All fp32. LDS 58.4 KB -> 2 blocks/CU.
__global__ __launch_bounds__(256, 2) void k_main(
    const float* __restrict__ x, const int* __restrict__ xm,
    const float* __restrict__ hour_emb, const float* __restrict__ wday_emb,
    const float* __restrict__ twT, const float* __restrict__ twb,
    const int* __restrict__ row_ptr, const int* __restrict__ csr_src,
    const float* __restrict__ csr_coef, const float* __restrict__ csum,
    const float* __restrict__ QT, const float* __restrict__ CW,
    const float* __restrict__ b1, const float* __restrict__ W2,
    const float* __restrict__ b2, float* __restrict__ out) {
  __shared__ float x4[1024][4];    // 16 KB  x-patch [s][k]
  __shared__ float4 qv[1024];      // 16 KB  QT rows
  __shared__ float csv[1024];      //  4 KB  coef row-sums
  __shared__ float4 xb4[1024];     // 16 KB  gathered xbar
  __shared__ float yL[512];        //  2 KB  y[g][o]
  __shared__ float sL[512];        //  2 KB  hour+wday [o][k]
  __shared__ float teL[2][128];    //  1 KB  time-dot halves
  int tid = threadIdx.x;
  int b = blockIdx.x;
  int n = b / TPP, tp = b % TPP;

  // ---- stage ----
  const float* xb = x + ((size_t)n * TT + tp * 4) * HH;
  for (int i = tid; i < 4096; i += 256) {
    int s = i & 1023, k = i >> 10;  // i = k*1024+s, coalesced read
    x4[s][k] = xb[i];
  }
  for (int i = tid; i < 1024; i += 256) {
    qv[i] = ((const float4*)QT)[i];
    csv[i] = csum[i];
  }
  yL[tid] = 0.f;
  yL[tid + 256] = 0.f;
  {
    int o = tid & 127, half = tid >> 7;
    for (int kk = half * 2; kk < half * 2 + 2; ++kk) {
      int t = tp * 4 + kk;
      int wd = xm[(n * TT + t) * 2 + 0];
      int hr = xm[(n * TT + t) * 2 + 1];
      sL[o * 4 + kk] = hour_emb[hr * DD + o] + wday_emb[wd * DD + o];
    }
  }
  __syncthreads();

  // ---- phase A: per-row gather, 4 rows/thread ----
  for (int u = 0; u < 4; ++u) {
    int h = u * 256 + tid;
    int j0 = row_ptr[h], j1 = row_ptr[h + 1];
    float a0 = 0.f, a1 = 0.f, a2 = 0.f, a3 = 0.f;
    for (int j = j0; j < j1; ++j) {
      int s = csr_src[j];
      float cf = csr_coef[j];
      float4 xv = *(const float4*)&x4[s][0];
      a0 = fmaf(cf, xv.x, a0);
      a1 = fmaf(cf, xv.y, a1);
      a2 = fmaf(cf, xv.z, a2);
      a3 = fmaf(cf, xv.w, a3);
    }
    xb4[h] = make_float4(a0, a1, a2, a3);
  }
  // ---- time-dot (coalesced twT, split over halves) ----
  {
    int o = tid & 127, half = tid >> 7;
    float p0 = (half == 0) ? twb[o] : 0.f;
    float p1 = 0.f, p2 = 0.f, p3 = 0.f;
    int j0 = half * 256;
    for (int j = j0; j < j0 + 256; j += 4) {
      p0 = fmaf(sL[j + 0], twT[(j + 0) * DD + o], p0);
      p1 = fmaf(sL[j + 1], twT[(j + 1) * DD + o], p1);
      p2 = fmaf(sL[j + 2], twT[(j + 2) * DD + o], p2);
      p3 = fmaf(sL[j + 3], twT[(j + 3) * DD + o], p3);
    }
    teL[half][o] = (p0 + p1) + (p2 + p3);
  }
  // phase-B constants (4 o-columns per thread)
  int o2 = tid & 31, sub = tid >> 5;
  float4 cw0 = *(const float4*)(CW + 0 * DD + o2 * 4);
  float4 cw1 = *(const float4*)(CW + 1 * DD + o2 * 4);
  float4 cw2 = *(const float4*)(CW + 2 * DD + o2 * 4);
  float4 cw3 = *(const float4*)(CW + 3 * DD + o2 * 4);
  float4 cw4 = *(const float4*)(CW + 4 * DD + o2 * 4);
  float4 b1v = *(const float4*)(b1 + o2 * 4);
  __syncthreads();

  // ---- phase B: relu(xbar5 @ CW + b1), Q-weighted reduce; 128 h per sub ----
  float ya[4][4];
#pragma unroll
  for (int g = 0; g < 4; ++g)
#pragma unroll
    for (int c = 0; c < 4; ++c) ya[g][c] = 0.f;
#pragma unroll 2
  for (int hh = sub * 128; hh < sub * 128 + 128; ++hh) {
    float4 xv = xb4[hh];
    float cs = csv[hh];
    float4 q = qv[hh];
    float t0 = fmaf(cs, cw4.x, b1v.x);
    t0 = fmaf(xv.x, cw0.x, t0); t0 = fmaf(xv.y, cw1.x, t0);
    t0 = fmaf(xv.z, cw2.x, t0); t0 = fmaf(xv.w, cw3.x, t0);
    t0 = fmaxf(t0, 0.f);
    float t1 = fmaf(cs, cw4.y, b1v.y);
    t1 = fmaf(xv.x, cw0.y, t1); t1 = fmaf(xv.y, cw1.y, t1);
    t1 = fmaf(xv.z, cw2.y, t1); t1 = fmaf(xv.w, cw3.y, t1);
    t1 = fmaxf(t1, 0.f);
    float t2 = fmaf(cs, cw4.z, b1v.z);
    t2 = fmaf(xv.x, cw0.z, t2); t2 = fmaf(xv.y, cw1.z, t2);
    t2 = fmaf(xv.z, cw2.z, t2); t2 = fmaf(xv.w, cw3.z, t2);
    t2 = fmaxf(t2, 0.f);
    float t3 = fmaf(cs, cw4.w, b1v.w);
    t3 = fmaf(xv.x, cw0.w, t3); t3 = fmaf(xv.y, cw1.w, t3);
    t3 = fmaf(xv.z, cw2.w, t3); t3 = fmaf(xv.w, cw3.w, t3);
    t3 = fmaxf(t3, 0.f);
    ya[0][0] = fmaf(q.x, t0, ya[0][0]); ya[0][1] = fmaf(q.x, t1, ya[0][1]);
    ya[0][2] = fmaf(q.x, t2, ya[0][2]); ya[0][3] = fmaf(q.x, t3, ya[0][3]);
    ya[1][0] = fmaf(q.y, t0, ya[1][0]); ya[1][1] = fmaf(q.y, t1, ya[1][1]);
    ya[1][2] = fmaf(q.y, t2, ya[1][2]); ya[1][3] = fmaf(q.y, t3, ya[1][3]);
    ya[2][0] = fmaf(q.z, t0, ya[2][0]); ya[2][1] = fmaf(q.z, t1, ya[2][1]);
    ya[2][2] = fmaf(q.z, t2, ya[2][2]); ya[2][3] = fmaf(q.z, t3, ya[2][3]);
    ya[3][0] = fmaf(q.w, t0, ya[3][0]); ya[3][1] = fmaf(q.w, t1, ya[3][1]);
    ya[3][2] = fmaf(q.w, t2, ya[3][2]); ya[3][3] = fmaf(q.w, t3, ya[3][3]);
  }
#pragma unroll
  for (int g = 0; g < 4; ++g)
#pragma unroll
    for (int c = 0; c < 4; ++c) atomicAdd(&yL[g * DD + o2 * 4 + c], ya[g][c]);
  __syncthreads();

  // ---- W2 epilogue + time add + both outputs ----
  {
    int o = tid & 127, gh = tid >> 7;
    int g0 = gh * 2, g1 = gh * 2 + 1;
    float z0 = b2[o], z1 = b2[o];
#pragma unroll 4
    for (int d = 0; d < DD; ++d) {
      float wv = W2[d * DD + o];
      z0 = fmaf(yL[g0 * DD + d], wv, z0);
      z1 = fmaf(yL[g1 * DD + d], wv, z1);
    }
    float tev = teL[0][o] + teL[1][o];
    size_t rb = ((size_t)n * TT + tp * 4) * DD;
    out[rb + g0 * DD + o] = z0 + tev;
    out[rb + g1 * DD + o] = z1 + tev;
    out[(size_t)NOUT + rb + g0 * DD + o] = tev;
    out[(size_t)NOUT + rb + g1 * DD + o] = tev;
  }
}

extern "C" void kernel_launch(void* const* d_in, const int* in_sizes, int n_in,
                              void* d_out, int out_size, void* d_ws, size_t ws_size,
                              hipStream_t stream) {
  const float* x = (const float*)d_in[0];
  const int* xm = (const int*)d_in[1];
  const int* edges = (const int*)d_in[2];
  const int* node_split = (const int*)d_in[3];
  const float* hour_emb = (const float*)d_in[4];
  const float* wday_emb = (const float*)d_in[5];
  const float* timeconv_w = (const float*)d_in[6];
  const float* timeconv_b = (const float*)d_in[7];
  const float* tcw = (const float*)d_in[8];
  const float* tcb = (const float*)d_in[9];
  const float* W1 = (const float*)d_in[10];
  const float* b1 = (const float*)d_in[11];
  const float* W2 = (const float*)d_in[12];
  const float* b2 = (const float*)d_in[13];
  float* out = (float*)d_out;

  char* w = (char*)d_ws;
  int* row_ptr = (int*)(w + 0);            //   4352 B
  int* csr_src = (int*)(w + 4352);         //  69632 B
  float* csr_coef = (float*)(w + 73984);   //  69632 B
  float* csum = (float*)(w + 143616);      //   4096 B
  float* QT = (float*)(w + 147712);        //  16384 B (16B aligned)
  float* CW = (float*)(w + 164096);        //   4096 B
  float* twT = (float*)(w + 168192);       // 262144 B (end ~430 KB)

  k_prep<<<130, 256, 0, stream>>>(edges, node_split, tcw, tcb, W1, timeconv_w,
                                  row_ptr, csr_src, csr_coef, csum, QT, CW, twT);
  k_main<<<BB, 256, 0, stream>>>(x, xm, hour_emb, wday_emb, twT, timeconv_b, row_ptr,
                                 csr_src, csr_coef, csum, QT, CW, b1, W2, b2, out);
}

// Round 9
// 191.483 us; speedup vs baseline: 1.3667x; 1.0834x over previous
//
#include <hip/hip_runtime.h>
#include <hip/hip_bf16.h>

#define NN 8
#define TT 192
#define HH 1024
#define DD 128
#define TPP 48
#define EE 16384
#define NEDGE (EE + HH)      // 17408
#define BB (NN * TPP)        // 384
#define NOUT (NN * TT * DD)  // 196608

// ================= K0: prep (1024 threads/block, 34 blocks) =================
// bid 0: CSR build, edges register-cached (16 uint2/thread), all-LDS pipeline.
// bid 1: CW = Conv@W1 (5 x 128).
// bid 2..33: twT transpose (tw[o][ck] -> twT[ck][o]).
__global__ __launch_bounds__(1024) void k_prep(
    const int* __restrict__ edges, const int* __restrict__ node_split,
    const float* __restrict__ tcw, const float* __restrict__ tcb,
    const float* __restrict__ W1, const float* __restrict__ tw,
    int* __restrict__ row_ptr, int* __restrict__ csr_src,
    float* __restrict__ csr_coef, float* __restrict__ csum,
    float* __restrict__ QT, float* __restrict__ CW, float* __restrict__ twT) {
  int tid = threadIdx.x, bid = blockIdx.x;
  if (bid == 0) {
    __shared__ int degL[1024];
    __shared__ int fillL[1024];
    __shared__ float csumL[1024];
    __shared__ float QTL[4096];
    __shared__ int rpL[1025];
    __shared__ int invL[1024];
    __shared__ int wsumL[16];
    degL[tid] = 0;
    fillL[tid] = 0;
    csumL[tid] = 0.f;
#pragma unroll
    for (int u = 0; u < 4; ++u) QTL[u * 1024 + tid] = 0.f;
    invL[node_split[tid]] = tid;
    // register-cache all edges (coalesced, one cold pass)
    uint2 ev[16];
    const uint2* ep = (const uint2*)edges;
#pragma unroll
    for (int k = 0; k < 16; ++k) ev[k] = ep[k * 1024 + tid];
    __syncthreads();
#pragma unroll
    for (int k = 0; k < 16; ++k) atomicAdd(&degL[ev[k].y], 1);
    __syncthreads();
    // exclusive scan of (deg+1): 16 wave scans + wave-sum scan
    int v = degL[tid] + 1;
    int lane = tid & 63, wid = tid >> 6;
    int inc = v;
#pragma unroll
    for (int off = 1; off < 64; off <<= 1) {
      int u = __shfl_up(inc, off, 64);
      if (lane >= off) inc += u;
    }
    if (lane == 63) wsumL[wid] = inc;
    __syncthreads();
    if (tid < 64) {
      int s = (lane < 16) ? wsumL[lane] : 0;
#pragma unroll
      for (int off = 1; off < 16; off <<= 1) {
        int u = __shfl_up(s, off, 64);
        if (lane >= off) s += u;
      }
      if (lane < 16) wsumL[lane] = s;
    }
    __syncthreads();
    int base = wid ? wsumL[wid - 1] : 0;
    int ex = base + inc - v;  // exclusive prefix = row start
    rpL[tid] = ex;
    if (tid == 1023) rpL[1024] = ex + v;
    __syncthreads();
    row_ptr[tid] = ex;
    if (tid == 1023) row_ptr[1024] = rpL[1024];
    // scatter from registers
#pragma unroll
    for (int k = 0; k < 16; ++k) {
      int s = ev[k].x, dt = ev[k].y;
      float cf = rsqrtf((float)(degL[s] + 1) * (float)(degL[dt] + 1));
      int pos = atomicAdd(&fillL[dt], 1);
      int at = rpL[dt] + pos;
      csr_src[at] = s;
      csr_coef[at] = cf;
      atomicAdd(&csumL[dt], cf);
      atomicAdd(&QTL[s * 4 + (invL[dt] >> 8)], cf * (1.0f / 256.0f));
    }
    {  // self loop: s = dt = tid
      float dv = (float)(degL[tid] + 1);
      float cf = rsqrtf(dv * dv);
      int pos = atomicAdd(&fillL[tid], 1);
      int at = rpL[tid] + pos;
      csr_src[at] = tid;
      csr_coef[at] = cf;
      atomicAdd(&csumL[tid], cf);
      atomicAdd(&QTL[tid * 4 + (invL[tid] >> 8)], cf * (1.0f / 256.0f));
    }
    __syncthreads();
    csum[tid] = csumL[tid];
#pragma unroll
    for (int u = 0; u < 4; ++u) QT[u * 1024 + tid] = QTL[u * 1024 + tid];
  } else if (bid == 1) {
    // CW[j][o] = sum_d Conv[j][d]*W1[d][o];  Conv[j<4][d]=tcw[d*4+j], Conv[4][d]=tcb[d]
    if (tid < 640) {
      int jr = tid >> 7, o = tid & 127;
      float acc = 0.f;
      if (jr < 4)
        for (int d = 0; d < DD; ++d) acc = fmaf(tcw[d * 4 + jr], W1[d * DD + o], acc);
      else
        for (int d = 0; d < DD; ++d) acc = fmaf(tcb[d], W1[d * DD + o], acc);
      CW[jr * DD + o] = acc;
    }
  } else {
    int base = (bid - 2) * 2048;
#pragma unroll
    for (int u = 0; u < 2; ++u) {
      int ii = base + u * 1024 + tid;
      twT[(ii & 511) * DD + (ii >> 9)] = tw[ii];
    }
  }
}

// ================= K1: fused gather + conv-fold + Q-reduce + time + W2 =================
// One block per b. All fp32. LDS 57.4 KB -> 2 blocks/CU.
__global__ __launch_bounds__(256, 2) void k_main(
    const float* __restrict__ x, const int* __restrict__ xm,
    const float* __restrict__ hour_emb, const float* __restrict__ wday_emb,
    const float* __restrict__ twT, const float* __restrict__ twb,
    const int* __restrict__ row_ptr, const int* __restrict__ csr_src,
    const float* __restrict__ csr_coef, const float* __restrict__ csum,
    const float* __restrict__ QT, const float* __restrict__ CW,
    const float* __restrict__ b1, const float* __restrict__ W2,
    const float* __restrict__ b2, float* __restrict__ out) {
  __shared__ float x4[1024][4];    // 16 KB  x-patch [s][k]
  __shared__ float4 qv[1024];      // 16 KB  QT rows
  __shared__ float csv[1024];      //  4 KB  coef row-sums
  __shared__ float4 xb4[1024];     // 16 KB  gathered xbar
  __shared__ float yL[512];        //  2 KB  y[g][o]
  __shared__ float sL[512];        //  2 KB  hour+wday [o][k]
  __shared__ float teL[2][128];    //  1 KB  time-dot halves
  int tid = threadIdx.x;
  int b = blockIdx.x;
  int n = b / TPP, tp = b % TPP;

  // ---- stage ----
  const float* xb = x + ((size_t)n * TT + tp * 4) * HH;
  for (int i = tid; i < 4096; i += 256) {
    int s = i & 1023, k = i >> 10;  // i = k*1024+s, coalesced read
    x4[s][k] = xb[i];
  }
  for (int i = tid; i < 1024; i += 256) {
    qv[i] = ((const float4*)QT)[i];
    csv[i] = csum[i];
  }
  yL[tid] = 0.f;
  yL[tid + 256] = 0.f;
  {
    int o = tid & 127, half = tid >> 7;
    for (int kk = half * 2; kk < half * 2 + 2; ++kk) {
      int t = tp * 4 + kk;
      int wd = xm[(n * TT + t) * 2 + 0];
      int hr = xm[(n * TT + t) * 2 + 1];
      sL[o * 4 + kk] = hour_emb[hr * DD + o] + wday_emb[wd * DD + o];
    }
  }
  __syncthreads();

  // ---- phase A: per-row gather, 4 rows/thread, software-pipelined ----
  for (int u = 0; u < 4; ++u) {
    int h = u * 256 + tid;
    int j0 = row_ptr[h], j1 = row_ptr[h + 1];  // j1 > j0 always (self loop)
    float a0 = 0.f, a1 = 0.f, a2 = 0.f, a3 = 0.f;
    int s = csr_src[j0];
    float cf = csr_coef[j0];
    for (int j = j0; j < j1 - 1; ++j) {
      int s2 = csr_src[j + 1];
      float cf2 = csr_coef[j + 1];
      float4 xv = *(const float4*)&x4[s][0];
      a0 = fmaf(cf, xv.x, a0);
      a1 = fmaf(cf, xv.y, a1);
      a2 = fmaf(cf, xv.z, a2);
      a3 = fmaf(cf, xv.w, a3);
      s = s2;
      cf = cf2;
    }
    float4 xv = *(const float4*)&x4[s][0];
    a0 = fmaf(cf, xv.x, a0);
    a1 = fmaf(cf, xv.y, a1);
    a2 = fmaf(cf, xv.z, a2);
    a3 = fmaf(cf, xv.w, a3);
    xb4[h] = make_float4(a0, a1, a2, a3);
  }
  // ---- time-dot (coalesced twT, split over halves) ----
  {
    int o = tid & 127, half = tid >> 7;
    float p0 = (half == 0) ? twb[o] : 0.f;
    float p1 = 0.f, p2 = 0.f, p3 = 0.f;
    int j0 = half * 256;
    for (int j = j0; j < j0 + 256; j += 4) {
      p0 = fmaf(sL[j + 0], twT[(j + 0) * DD + o], p0);
      p1 = fmaf(sL[j + 1], twT[(j + 1) * DD + o], p1);
      p2 = fmaf(sL[j + 2], twT[(j + 2) * DD + o], p2);
      p3 = fmaf(sL[j + 3], twT[(j + 3) * DD + o], p3);
    }
    teL[half][o] = (p0 + p1) + (p2 + p3);
  }
  // phase-B constants (4 o-columns per thread)
  int o2 = tid & 31, sub = tid >> 5;
  float4 cw0 = *(const float4*)(CW + 0 * DD + o2 * 4);
  float4 cw1 = *(const float4*)(CW + 1 * DD + o2 * 4);
  float4 cw2 = *(const float4*)(CW + 2 * DD + o2 * 4);
  float4 cw3 = *(const float4*)(CW + 3 * DD + o2 * 4);
  float4 cw4 = *(const float4*)(CW + 4 * DD + o2 * 4);
  float4 b1v = *(const float4*)(b1 + o2 * 4);
  __syncthreads();

  // ---- phase B: relu(xbar5 @ CW + b1), Q-weighted reduce; 128 h per sub ----
  float ya[4][4];
#pragma unroll
  for (int g = 0; g < 4; ++g)
#pragma unroll
    for (int c = 0; c < 4; ++c) ya[g][c] = 0.f;
#pragma unroll 2
  for (int hh = sub * 128; hh < sub * 128 + 128; ++hh) {
    float4 xv = xb4[hh];
    float cs = csv[hh];
    float4 q = qv[hh];
    float t0 = fmaf(cs, cw4.x, b1v.x);
    t0 = fmaf(xv.x, cw0.x, t0); t0 = fmaf(xv.y, cw1.x, t0);
    t0 = fmaf(xv.z, cw2.x, t0); t0 = fmaf(xv.w, cw3.x, t0);
    t0 = fmaxf(t0, 0.f);
    float t1 = fmaf(cs, cw4.y, b1v.y);
    t1 = fmaf(xv.x, cw0.y, t1); t1 = fmaf(xv.y, cw1.y, t1);
    t1 = fmaf(xv.z, cw2.y, t1); t1 = fmaf(xv.w, cw3.y, t1);
    t1 = fmaxf(t1, 0.f);
    float t2 = fmaf(cs, cw4.z, b1v.z);
    t2 = fmaf(xv.x, cw0.z, t2); t2 = fmaf(xv.y, cw1.z, t2);
    t2 = fmaf(xv.z, cw2.z, t2); t2 = fmaf(xv.w, cw3.z, t2);
    t2 = fmaxf(t2, 0.f);
    float t3 = fmaf(cs, cw4.w, b1v.w);
    t3 = fmaf(xv.x, cw0.w, t3); t3 = fmaf(xv.y, cw1.w, t3);
    t3 = fmaf(xv.z, cw2.w, t3); t3 = fmaf(xv.w, cw3.w, t3);
    t3 = fmaxf(t3, 0.f);
    ya[0][0] = fmaf(q.x, t0, ya[0][0]); ya[0][1] = fmaf(q.x, t1, ya[0][1]);
    ya[0][2] = fmaf(q.x, t2, ya[0][2]); ya[0][3] = fmaf(q.x, t3, ya[0][3]);
    ya[1][0] = fmaf(q.y, t0, ya[1][0]); ya[1][1] = fmaf(q.y, t1, ya[1][1]);
    ya[1][2] = fmaf(q.y, t2, ya[1][2]); ya[1][3] = fmaf(q.y, t3, ya[1][3]);
    ya[2][0] = fmaf(q.z, t0, ya[2][0]); ya[2][1] = fmaf(q.z, t1, ya[2][1]);
    ya[2][2] = fmaf(q.z, t2, ya[2][2]); ya[2][3] = fmaf(q.z, t3, ya[2][3]);
    ya[3][0] = fmaf(q.w, t0, ya[3][0]); ya[3][1] = fmaf(q.w, t1, ya[3][1]);
    ya[3][2] = fmaf(q.w, t2, ya[3][2]); ya[3][3] = fmaf(q.w, t3, ya[3][3]);
  }
#pragma unroll
  for (int g = 0; g < 4; ++g)
#pragma unroll
    for (int c = 0; c < 4; ++c) atomicAdd(&yL[g * DD + o2 * 4 + c], ya[g][c]);
  __syncthreads();

  // ---- W2 epilogue + time add + both outputs ----
  {
    int o = tid & 127, gh = tid >> 7;
    int g0 = gh * 2, g1 = gh * 2 + 1;
    float z0 = b2[o], z1 = b2[o];
#pragma unroll 4
    for (int d = 0; d < DD; ++d) {
      float wv = W2[d * DD + o];
      z0 = fmaf(yL[g0 * DD + d], wv, z0);
      z1 = fmaf(yL[g1 * DD + d], wv, z1);
    }
    float tev = teL[0][o] + teL[1][o];
    size_t rb = ((size_t)n * TT + tp * 4) * DD;
    out[rb + g0 * DD + o] = z0 + tev;
    out[rb + g1 * DD + o] = z1 + tev;
    out[(size_t)NOUT + rb + g0 * DD + o] = tev;
    out[(size_t)NOUT + rb + g1 * DD + o] = tev;
  }
}

extern "C" void kernel_launch(void* const* d_in, const int* in_sizes, int n_in,
                              void* d_out, int out_size, void* d_ws, size_t ws_size,
                              hipStream_t stream) {
  const float* x = (const float*)d_in[0];
  const int* xm = (const int*)d_in[1];
  const int* edges = (const int*)d_in[2];
  const int* node_split = (const int*)d_in[3];
  const float* hour_emb = (const float*)d_in[4];
  const float* wday_emb = (const float*)d_in[5];
  const float* timeconv_w = (const float*)d_in[6];
  const float* timeconv_b = (const float*)d_in[7];
  const float* tcw = (const float*)d_in[8];
  const float* tcb = (const float*)d_in[9];
  const float* W1 = (const float*)d_in[10];
  const float* b1 = (const float*)d_in[11];
  const float* W2 = (const float*)d_in[12];
  const float* b2 = (const float*)d_in[13];
  float* out = (float*)d_out;

  char* w = (char*)d_ws;
  int* row_ptr = (int*)(w + 0);            //   4352 B
  int* csr_src = (int*)(w + 4352);         //  69632 B
  float* csr_coef = (float*)(w + 73984);   //  69632 B
  float* csum = (float*)(w + 143616);      //   4096 B
  float* QT = (float*)(w + 147712);        //  16384 B (16B aligned)
  float* CW = (float*)(w + 164096);        //   4096 B
  float* twT = (float*)(w + 168192);       // 262144 B (end ~430 KB)

  k_prep<<<34, 1024, 0, stream>>>(edges, node_split, tcw, tcb, W1, timeconv_w,
                                  row_ptr, csr_src, csr_coef, csum, QT, CW, twT);
  k_main<<<BB, 256, 0, stream>>>(x, xm, hour_emb, wday_emb, twT, timeconv_b, row_ptr,
                                 csr_src, csr_coef, csum, QT, CW, b1, W2, b2, out);
}

// Round 10
// 178.876 us; speedup vs baseline: 1.4630x; 1.0705x over previous
//
#include <hip/hip_runtime.h>
#include <hip/hip_bf16.h>

#define NN 8
#define TT 192
#define HH 1024
#define DD 128
#define TPP 48
#define EE 16384
#define NEDGE (EE + HH)      // 17408
#define BB (NN * TPP)        // 384
#define NOUT (NN * TT * DD)  // 196608

// ================= K0: deg atomics | twT | CW | inv (198 blocks x 256) =================
__global__ __launch_bounds__(256) void k_pre(
    const int* __restrict__ edges, int* __restrict__ degE,
    const int* __restrict__ node_split, int* __restrict__ inv,
    const float* __restrict__ tcw, const float* __restrict__ tcb,
    const float* __restrict__ W1, float* __restrict__ CW,
    const float* __restrict__ tw, float* __restrict__ twT) {
  int tid = threadIdx.x, bid = blockIdx.x;
  if (bid < 68) {
    int e = bid * 256 + tid;
    if (e < EE) atomicAdd(&degE[edges[2 * e + 1]], 1);
  } else if (bid < 196) {
    int base = (bid - 68) * 512;
#pragma unroll
    for (int u = 0; u < 2; ++u) {
      int ii = base + u * 256 + tid;
      twT[(ii & 511) * DD + (ii >> 9)] = tw[ii];
    }
  } else if (bid == 196) {
    // CW[j][o] = sum_d Conv[j][d]*W1[d][o]; Conv[j<4][d]=tcw[d*4+j], Conv[4][d]=tcb[d]
    for (int j = tid; j < 640; j += 256) {
      int jr = j >> 7, o = j & 127;
      float acc = 0.f;
      if (jr < 4)
        for (int d = 0; d < DD; ++d) acc = fmaf(tcw[d * 4 + jr], W1[d * DD + o], acc);
      else
        for (int d = 0; d < DD; ++d) acc = fmaf(tcb[d], W1[d * DD + o], acc);
      CW[jr * DD + o] = acc;
    }
  } else {
    for (int i = tid; i < 1024; i += 256) inv[node_split[i]] = i;
  }
}

// ================= K1: exclusive scan of (deg+1) -> row_ptr (1 block) =================
__global__ __launch_bounds__(1024) void k_scan(const int* __restrict__ degE,
                                               int* __restrict__ row_ptr) {
  __shared__ int wsumL[16];
  int tid = threadIdx.x;
  int v = degE[tid] + 1;
  int lane = tid & 63, wid = tid >> 6;
  int inc = v;
#pragma unroll
  for (int off = 1; off < 64; off <<= 1) {
    int u = __shfl_up(inc, off, 64);
    if (lane >= off) inc += u;
  }
  if (lane == 63) wsumL[wid] = inc;
  __syncthreads();
  if (tid < 64) {
    int s = (lane < 16) ? wsumL[lane] : 0;
#pragma unroll
    for (int off = 1; off < 16; off <<= 1) {
      int u = __shfl_up(s, off, 64);
      if (lane >= off) s += u;
    }
    if (lane < 16) wsumL[lane] = s;
  }
  __syncthreads();
  int base = wid ? wsumL[wid - 1] : 0;
  row_ptr[tid] = base + inc - v;
  if (tid == 1023) row_ptr[1024] = base + inc;
}

// ================= K2: scatter (68 blocks) =================
__global__ __launch_bounds__(256) void k_scatter(
    const int* __restrict__ edges, const int* __restrict__ degE,
    const int* __restrict__ row_ptr, const int* __restrict__ inv,
    int* __restrict__ fill, int* __restrict__ csr_src, float* __restrict__ csr_coef,
    float* __restrict__ csum, float* __restrict__ QT) {
  int e = blockIdx.x * 256 + threadIdx.x;
  if (e >= NEDGE) return;
  int s, dt;
  if (e < EE) { s = edges[2 * e]; dt = edges[2 * e + 1]; }
  else        { s = dt = e - EE; }
  float cf = rsqrtf((float)(degE[s] + 1) * (float)(degE[dt] + 1));
  int pos = atomicAdd(&fill[dt], 1);
  int at = row_ptr[dt] + pos;
  csr_src[at] = s;
  csr_coef[at] = cf;
  atomicAdd(&csum[dt], cf);
  atomicAdd(&QT[s * 4 + (inv[dt] >> 8)], cf * (1.0f / 256.0f));
}

// ================= K3: fused gather + conv-fold + Q-reduce + time + W2 =================
// One block per b, 512 threads. All fp32. LDS 58 KB -> 2 blocks/CU, 16 waves/CU.
__global__ __launch_bounds__(512, 4) void k_main(
    const float* __restrict__ x, const int* __restrict__ xm,
    const float* __restrict__ hour_emb, const float* __restrict__ wday_emb,
    const float* __restrict__ twT, const float* __restrict__ twb,
    const int* __restrict__ row_ptr, const int* __restrict__ csr_src,
    const float* __restrict__ csr_coef, const float* __restrict__ csum,
    const float* __restrict__ QT, const float* __restrict__ CW,
    const float* __restrict__ b1, const float* __restrict__ W2,
    const float* __restrict__ b2, float* __restrict__ out) {
  __shared__ float x4[1024][4];    // 16 KB  x-patch [s][k]
  __shared__ float4 qv[1024];      // 16 KB  QT rows
  __shared__ float csv[1024];      //  4 KB  coef row-sums
  __shared__ float4 xb4[1024];     // 16 KB  gathered xbar
  __shared__ float yL[512];        //  2 KB  y[g][o]
  __shared__ float sL[512];        //  2 KB  hour+wday [o][k]
  __shared__ float teL[4][128];    //  2 KB  time-dot quarters
  int tid = threadIdx.x;
  int b = blockIdx.x;
  int n = b / TPP, tp = b % TPP;

  // ---- stage ----
  const float* xb = x + ((size_t)n * TT + tp * 4) * HH;
#pragma unroll
  for (int i = tid; i < 4096; i += 512) {
    int s = i & 1023, k = i >> 10;  // i = k*1024+s, coalesced read
    x4[s][k] = xb[i];
  }
#pragma unroll
  for (int i = tid; i < 1024; i += 512) {
    qv[i] = ((const float4*)QT)[i];
    csv[i] = csum[i];
  }
  yL[tid] = 0.f;
  {
    int o = tid & 127, kk = tid >> 7;
    int t = tp * 4 + kk;
    int wd = xm[(n * TT + t) * 2 + 0];
    int hr = xm[(n * TT + t) * 2 + 1];
    sL[o * 4 + kk] = hour_emb[hr * DD + o] + wday_emb[wd * DD + o];
  }
  __syncthreads();

  // ---- phase A: per-row gather, 2 rows/thread, software-pipelined ----
  for (int u = 0; u < 2; ++u) {
    int h = u * 512 + tid;
    int j0 = row_ptr[h], j1 = row_ptr[h + 1];  // j1 > j0 always (self loop)
    float a0 = 0.f, a1 = 0.f, a2 = 0.f, a3 = 0.f;
    int s = csr_src[j0];
    float cf = csr_coef[j0];
    for (int j = j0; j < j1 - 1; ++j) {
      int s2 = csr_src[j + 1];
      float cf2 = csr_coef[j + 1];
      float4 xv = *(const float4*)&x4[s][0];
      a0 = fmaf(cf, xv.x, a0);
      a1 = fmaf(cf, xv.y, a1);
      a2 = fmaf(cf, xv.z, a2);
      a3 = fmaf(cf, xv.w, a3);
      s = s2;
      cf = cf2;
    }
    float4 xv = *(const float4*)&x4[s][0];
    a0 = fmaf(cf, xv.x, a0);
    a1 = fmaf(cf, xv.y, a1);
    a2 = fmaf(cf, xv.z, a2);
    a3 = fmaf(cf, xv.w, a3);
    xb4[h] = make_float4(a0, a1, a2, a3);
  }
  // ---- time-dot (coalesced twT, split over quarters) ----
  {
    int o = tid & 127, qq = tid >> 7;
    float p0 = (qq == 0) ? twb[o] : 0.f;
    float p1 = 0.f, p2 = 0.f, p3 = 0.f;
    int j0 = qq * 128;
    for (int j = j0; j < j0 + 128; j += 4) {
      p0 = fmaf(sL[j + 0], twT[(j + 0) * DD + o], p0);
      p1 = fmaf(sL[j + 1], twT[(j + 1) * DD + o], p1);
      p2 = fmaf(sL[j + 2], twT[(j + 2) * DD + o], p2);
      p3 = fmaf(sL[j + 3], twT[(j + 3) * DD + o], p3);
    }
    teL[qq][o] = (p0 + p1) + (p2 + p3);
  }
  // phase-B constants (4 o-columns per thread)
  int o2 = tid & 31, sub = tid >> 5;  // 16 subs x 64 h
  float4 cw0 = *(const float4*)(CW + 0 * DD + o2 * 4);
  float4 cw1 = *(const float4*)(CW + 1 * DD + o2 * 4);
  float4 cw2 = *(const float4*)(CW + 2 * DD + o2 * 4);
  float4 cw3 = *(const float4*)(CW + 3 * DD + o2 * 4);
  float4 cw4 = *(const float4*)(CW + 4 * DD + o2 * 4);
  float4 b1v = *(const float4*)(b1 + o2 * 4);
  __syncthreads();

  // ---- phase B: relu(xbar5 @ CW + b1), Q-weighted reduce; 64 h per sub ----
  float ya[4][4];
#pragma unroll
  for (int g = 0; g < 4; ++g)
#pragma unroll
    for (int c = 0; c < 4; ++c) ya[g][c] = 0.f;
#pragma unroll 2
  for (int hh = sub * 64; hh < sub * 64 + 64; ++hh) {
    float4 xv = xb4[hh];
    float cs = csv[hh];
    float4 q = qv[hh];
    float t0 = fmaf(cs, cw4.x, b1v.x);
    t0 = fmaf(xv.x, cw0.x, t0); t0 = fmaf(xv.y, cw1.x, t0);
    t0 = fmaf(xv.z, cw2.x, t0); t0 = fmaf(xv.w, cw3.x, t0);
    t0 = fmaxf(t0, 0.f);
    float t1 = fmaf(cs, cw4.y, b1v.y);
    t1 = fmaf(xv.x, cw0.y, t1); t1 = fmaf(xv.y, cw1.y, t1);
    t1 = fmaf(xv.z, cw2.y, t1); t1 = fmaf(xv.w, cw3.y, t1);
    t1 = fmaxf(t1, 0.f);
    float t2 = fmaf(cs, cw4.z, b1v.z);
    t2 = fmaf(xv.x, cw0.z, t2); t2 = fmaf(xv.y, cw1.z, t2);
    t2 = fmaf(xv.z, cw2.z, t2); t2 = fmaf(xv.w, cw3.z, t2);
    t2 = fmaxf(t2, 0.f);
    float t3 = fmaf(cs, cw4.w, b1v.w);
    t3 = fmaf(xv.x, cw0.w, t3); t3 = fmaf(xv.y, cw1.w, t3);
    t3 = fmaf(xv.z, cw2.w, t3); t3 = fmaf(xv.w, cw3.w, t3);
    t3 = fmaxf(t3, 0.f);
    ya[0][0] = fmaf(q.x, t0, ya[0][0]); ya[0][1] = fmaf(q.x, t1, ya[0][1]);
    ya[0][2] = fmaf(q.x, t2, ya[0][2]); ya[0][3] = fmaf(q.x, t3, ya[0][3]);
    ya[1][0] = fmaf(q.y, t0, ya[1][0]); ya[1][1] = fmaf(q.y, t1, ya[1][1]);
    ya[1][2] = fmaf(q.y, t2, ya[1][2]); ya[1][3] = fmaf(q.y, t3, ya[1][3]);
    ya[2][0] = fmaf(q.z, t0, ya[2][0]); ya[2][1] = fmaf(q.z, t1, ya[2][1]);
    ya[2][2] = fmaf(q.z, t2, ya[2][2]); ya[2][3] = fmaf(q.z, t3, ya[2][3]);
    ya[3][0] = fmaf(q.w, t0, ya[3][0]); ya[3][1] = fmaf(q.w, t1, ya[3][1]);
    ya[3][2] = fmaf(q.w, t2, ya[3][2]); ya[3][3] = fmaf(q.w, t3, ya[3][3]);
  }
#pragma unroll
  for (int g = 0; g < 4; ++g)
#pragma unroll
    for (int c = 0; c < 4; ++c) atomicAdd(&yL[g * DD + o2 * 4 + c], ya[g][c]);
  __syncthreads();

  // ---- W2 epilogue + time add + both outputs (one g per thread-quarter) ----
  {
    int o = tid & 127, g = tid >> 7;
    float a0 = b2[o], a1 = 0.f, a2 = 0.f, a3 = 0.f;
#pragma unroll 4
    for (int d = 0; d < DD; d += 4) {
      a0 = fmaf(yL[g * DD + d + 0], W2[(d + 0) * DD + o], a0);
      a1 = fmaf(yL[g * DD + d + 1], W2[(d + 1) * DD + o], a1);
      a2 = fmaf(yL[g * DD + d + 2], W2[(d + 2) * DD + o], a2);
      a3 = fmaf(yL[g * DD + d + 3], W2[(d + 3) * DD + o], a3);
    }
    float tev = (teL[0][o] + teL[1][o]) + (teL[2][o] + teL[3][o]);
    size_t rb = ((size_t)n * TT + tp * 4) * DD;
    out[rb + g * DD + o] = (a0 + a1) + (a2 + a3) + tev;
    out[(size_t)NOUT + rb + g * DD + o] = tev;
  }
}

extern "C" void kernel_launch(void* const* d_in, const int* in_sizes, int n_in,
                              void* d_out, int out_size, void* d_ws, size_t ws_size,
                              hipStream_t stream) {
  const float* x = (const float*)d_in[0];
  const int* xm = (const int*)d_in[1];
  const int* edges = (const int*)d_in[2];
  const int* node_split = (const int*)d_in[3];
  const float* hour_emb = (const float*)d_in[4];
  const float* wday_emb = (const float*)d_in[5];
  const float* timeconv_w = (const float*)d_in[6];
  const float* timeconv_b = (const float*)d_in[7];
  const float* tcw = (const float*)d_in[8];
  const float* tcb = (const float*)d_in[9];
  const float* W1 = (const float*)d_in[10];
  const float* b1 = (const float*)d_in[11];
  const float* W2 = (const float*)d_in[12];
  const float* b2 = (const float*)d_in[13];
  float* out = (float*)d_out;

  char* w = (char*)d_ws;
  int* degE = (int*)(w + 0);              //   4096 B (memset)
  int* fill = (int*)(w + 4096);           //   4096 B (memset)
  float* csum = (float*)(w + 8192);       //   4096 B (memset)
  float* QT = (float*)(w + 12288);        //  16384 B (memset; 16B aligned)
  int* row_ptr = (int*)(w + 28672);       //   4352 B
  int* inv = (int*)(w + 33024);           //   4096 B
  int* csr_src = (int*)(w + 37120);       //  69632 B
  float* csr_coef = (float*)(w + 106752); //  69632 B
  float* CW = (float*)(w + 176384);       //   4096 B
  float* twT = (float*)(w + 180480);      // 262144 B (end ~442 KB)

  hipMemsetAsync(d_ws, 0, 28672, stream);
  k_pre<<<198, 256, 0, stream>>>(edges, degE, node_split, inv, tcw, tcb, W1, CW,
                                 timeconv_w, twT);
  k_scan<<<1, 1024, 0, stream>>>(degE, row_ptr);
  k_scatter<<<68, 256, 0, stream>>>(edges, degE, row_ptr, inv, fill, csr_src, csr_coef,
                                    csum, QT);
  k_main<<<BB, 512, 0, stream>>>(x, xm, hour_emb, wday_emb, twT, timeconv_b, row_ptr,
                                 csr_src, csr_coef, csum, QT, CW, b1, W2, b2, out);
}